// Round 8
// baseline (2055.684 us; speedup 1.0000x reference)
//
#include <hip/hip_runtime.h>

// Problem sizes
#define Bn 1024
#define Tn 168
#define En 8
#define Hn 512
#define Dn 4
#define On 24
#define G4 2048            // 4*H
#define HB (Bn*Hn)         // elements per h buffer plane

typedef short v8s __attribute__((ext_vector_type(8)));
typedef float v4f __attribute__((ext_vector_type(4)));

#define CAT2(a, b) a##b

__device__ __forceinline__ unsigned short f2bf(float f) {
  union { float f; unsigned u; } v; v.f = f;
  return (unsigned short)((v.u + 0x7fffu + ((v.u >> 16) & 1u)) >> 16);
}
__device__ __forceinline__ float bf2f(unsigned short s) {
  union { unsigned u; float f; } v; v.u = ((unsigned)s) << 16; return v.f;
}
__device__ __forceinline__ float sigm(float x) { return 1.f / (1.f + __expf(-x)); }
__device__ __forceinline__ float tanh_(float x) { return 1.f - 2.f / (__expf(2.f * x) + 1.f); }

// ---- flag ops: ALWAYS device-coherent sc0 sc1 (round-6 proven; the round-7
// atomic variant wrote through to HBM on every poll -> reverted). ----
#define STFLAG(p, v) do { unsigned __vv = (v); \
  asm volatile("global_store_dword %0, %1, off sc0 sc1" :: "v"(p), "v"(__vv) : "memory"); } while (0)
#define LDFLAG(r, p) \
  asm volatile("global_load_dword %0, %1, off sc0 sc1\n\ts_waitcnt vmcnt(0)" \
  : "=v"(r) : "v"(p) : "memory")

// ---- h-plane data ops, path-specialized ----
// D=0 (fast, group co-located on one XCD): plain stores (dirty in shared L2),
//   sc0 loads (L1 bypass, L2 hit). D=1 (slow): device-coherent sc0 sc1.
#define STH_0(p, v) do { unsigned __vv = (v); \
  asm volatile("global_store_short %0, %1, off" :: "v"(p), "v"(__vv) : "memory"); } while (0)
#define STH_1(p, v) do { unsigned __vv = (v); \
  asm volatile("global_store_short %0, %1, off sc0 sc1" :: "v"(p), "v"(__vv) : "memory"); } while (0)
#define LDC_0(dst, p) asm volatile("global_load_dwordx4 %0, %1, off sc0" : "=&v"(dst) : "v"(p))
#define LDC_1(dst, p) asm volatile("global_load_dwordx4 %0, %1, off sc0 sc1" : "=&v"(dst) : "v"(p))

#define WAITV(N) do { \
  asm volatile("s_waitcnt vmcnt(" #N ")" ::: "memory"); \
  __builtin_amdgcn_sched_barrier(0); } while (0)

// ---------------- setup kernels ----------------

__global__ void setup_weights(const float* __restrict__ whh_enc,
                              const float* __restrict__ whh_dec,
                              const float* __restrict__ wih_dec,
                              const float* __restrict__ wfc,
                              unsigned short* __restrict__ whh_bf,
                              unsigned short* __restrict__ weff_bf) {
  int idx = blockIdx.x * 256 + threadIdx.x;
  if (idx >= G4 * Hn) return;
  int r = idx >> 9, c = idx & 511;
  whh_bf[idx] = f2bf(whh_enc[idx]);
  float a = whh_dec[idx];
#pragma unroll
  for (int d = 0; d < 4; d++) a += wih_dec[r * 4 + d] * wfc[d * Hn + c];
  weff_bf[idx] = f2bf(a);
}

__global__ void setup_misc(const float* __restrict__ b_dec,
                           const float* __restrict__ wih_dec,
                           const float* __restrict__ b_fc,
                           float* __restrict__ beff,
                           float* __restrict__ out,
                           unsigned int* __restrict__ flags,
                           float* __restrict__ dpart) {
  int idx = blockIdx.x * 256 + threadIdx.x;
  if (idx < Bn * On) out[idx] = 0.f;
  if (idx < G4) {
    float a = b_dec[idx];
#pragma unroll
    for (int d = 0; d < 4; d++) a += wih_dec[idx * 4 + d] * b_fc[d];
    beff[idx] = a;
  }
  if (idx < 256 * 64) flags[idx] = 0u;   // 256 flags, 256B stride
  if (idx < 16 * 64 * 4) dpart[idx] = 0.f;
}

// ---------------- persistent LSTM kernel ----------------
// 256 blocks x 256 threads, 1 block/CU. group g = blockIdx%16 owns batch rows
// [64g,64g+64); member jj = blockIdx/16 owns hiddens [32jj,32jj+32).
// NEW wave tiling: wave (p,q) with p=wid>>1, q=wid&1 computes batch rows
// [32p,32p+32) x hiddens [16q,16q+16) (all 4 gates). B panel in LDS reordered
// to [q][gate][hid][K] so each wave streams only ITS 32KB quarter -> CU LDS
// traffic 512KB->256KB per step; each B fragment feeds 4 MFMAs.
// Flag protocol: value = #h produced; step t polls >= t+1, sets t+2 (sc0 sc1).
// h-plane fast path (same-XCD group, runtime-verified): plain store/sc0 load.

__global__ void __launch_bounds__(256, 1) lstm_main(
    const float* __restrict__ x,
    const float* __restrict__ wih_enc,
    const float* __restrict__ b_enc,
    const float* __restrict__ wih_dec,
    const float* __restrict__ wfc,
    const float* __restrict__ bfc,
    const unsigned short* __restrict__ whh_bf,
    const unsigned short* __restrict__ weff_bf,
    const float* __restrict__ beff,
    unsigned short* __restrict__ hbuf,   // [2][B*H] hi plane
    unsigned short* __restrict__ lbuf,   // [2][B*H] lo plane
    float* __restrict__ out,
    unsigned int* __restrict__ flags,    // 256 x 64 u32 (256B stride)
    unsigned int* __restrict__ xcds,     // 256 u32: member -> XCC id
    float* __restrict__ dpart) {         // [16][64][4] partial h_enc@Wfc^T
  __shared__ __align__(16) unsigned short wlds[128 * 512];  // 128KB, swizzled
  __shared__ __align__(16) float xwp[128][12];   // W_ih strip, padded rows
  __shared__ float xwdt[4][128];                 // W_ih_dec strip, transposed
  __shared__ float biasl[128];
  __shared__ float wfcs[4][32];
  __shared__ __align__(16) float xsp[4][32][12]; // per-wave x strip, padded
  __shared__ float dl0[64][4];
  __shared__ float bfc3s;
  __shared__ unsigned scnt;

  const int tid = threadIdx.x;
  const int wid = tid >> 6;
  const int lane = tid & 63;
  const int cidx = lane & 15;
  const int kb = lane >> 4;
  const int sw = cidx & 7;
  const int p = wid >> 1;        // batch half (0,1)
  const int q = wid & 1;         // hidden half (0,1)
  const int q64 = q * 64;
  const int g = blockIdx.x & 15;
  const int jj = blockIdx.x >> 4;
  const int bb = g * 64;
  unsigned* myflag = flags + (((g << 4) + jj) << 6);
  const unsigned* fpoll = flags + (((g << 4) + cidx) << 6);

  unsigned xcc;
  asm volatile("s_getreg_b32 %0, hwreg(HW_REG_XCC_ID)" : "=s"(xcc));

  // LDS row rl (0..127) -> global gate row: q_=rl>>6, nt_=(rl>>4)&3, hid=rl&15
  // gr = nt_*512 + jj*32 + q_*16 + hid
#define GR_OF(rl) ((((rl) >> 4) & 3) * 512 + jj * 32 + ((rl) >> 6) * 16 + ((rl) & 15))

  // ---- phase 0: LDS fills + h zeroing (sc1) + xcds publish ----
  {
    if (tid == 0) scnt = 0u;
    float4* wq4 = (float4*)wlds;
    for (int i = tid; i < 128 * 64; i += 256) {
      int rl = i >> 6, ch = i & 63;
      int gr = GR_OF(rl);
      wq4[rl * 64 + (ch ^ (rl & 7))] = *(const float4*)(whh_bf + (size_t)gr * Hn + ch * 8);
    }
    for (int i = tid; i < 128 * 8; i += 256) {
      int c = i & 127, e = i >> 7;
      int gr = GR_OF(c);
      xwp[c][e] = wih_enc[gr * En + e];
    }
    for (int i = tid; i < 128 * 4; i += 256) {
      int c = i & 127, d = i >> 7;
      int gr = GR_OF(c);
      xwdt[d][c] = wih_dec[gr * Dn + d];
    }
    for (int i = tid; i < 128; i += 256) {
      int gr = GR_OF(i);
      biasl[i] = b_enc[gr];
    }
    if (tid < 128) wfcs[tid >> 5][tid & 31] = wfc[(tid >> 5) * Hn + jj * 32 + (tid & 31)];
    if (tid == 0) bfc3s = bfc[3];
    for (int i = tid; i < 64 * 32; i += 256) {
      int m = bb + (i >> 5), j = jj * 32 + (i & 31);
      STH_1(hbuf + (size_t)m * Hn + j, 0);
      STH_1(lbuf + (size_t)m * Hn + j, 0);
    }
    if (tid == 0) {
      unsigned* xp = xcds + ((g << 4) + jj);
      asm volatile("global_store_dword %0, %1, off sc0 sc1" :: "v"(xp), "v"(xcc) : "memory");
    }
  }
  asm volatile("s_waitcnt vmcnt(0)" ::: "memory");
  __syncthreads();
  if (tid == 0) STFLAG(myflag, 1u);   // h_0 + xcds available

#define POLL(TGT) do { \
    int guard = 0; \
    while (true) { \
      unsigned fv = 0xFFFFFFFFu; \
      if (lane < 16) { LDFLAG(fv, fpoll); } \
      if (__ballot(fv < (unsigned)(TGT)) == 0ull) break; \
      __builtin_amdgcn_s_sleep(1); \
      if (++guard > (1 << 21)) break; \
    } } while (0)

  // ---- co-location check ----
  POLL(1);
  unsigned other = xcc;
  if (lane < 16) {
    const unsigned* xq = xcds + ((g << 4) + cidx);
    asm volatile("global_load_dword %0, %1, off sc0 sc1\n\ts_waitcnt vmcnt(0)"
                 : "=v"(other) : "v"(xq) : "memory");
  }
  const int fast = (__ballot(other != xcc) == 0ull) ? 1 : 0;

  float cst[2][4];
#pragma unroll
  for (int a = 0; a < 2; a++)
#pragma unroll
    for (int r = 0; r < 4; r++) cst[a][r] = 0.f;

  const v8s* wq = (const v8s*)wlds;
  const int am0 = (bb + p * 32 + cidx) * Hn + kb * 8;
  const int am1 = am0 + 16 * Hn;

#define ISSUE(D, BH, BL, KT0) \
  _Pragma("unroll") for (int kk = 0; kk < 2; kk++) { \
    CAT2(LDC_, D)(BH[kk * 2 + 0], (const v8s*)(hsrc + am0 + (KT0 + kk) * 32)); \
    CAT2(LDC_, D)(BH[kk * 2 + 1], (const v8s*)(hsrc + am1 + (KT0 + kk) * 32)); \
    CAT2(LDC_, D)(BL[kk * 2 + 0], (const v8s*)(lsrc + am0 + (KT0 + kk) * 32)); \
    CAT2(LDC_, D)(BL[kk * 2 + 1], (const v8s*)(lsrc + am1 + (KT0 + kk) * 32)); }

#define MMC(BH, BL, KT0) \
  _Pragma("unroll") for (int kk = 0; kk < 2; kk++) \
    _Pragma("unroll") for (int nt = 0; nt < 4; nt++) { \
      v8s bfr = wq[(q64 + nt * 16 + cidx) * 64 + ((((KT0 + kk) * 4) + kb) ^ sw)]; \
      acc[0][nt] = __builtin_amdgcn_mfma_f32_16x16x32_bf16(BH[kk * 2 + 0], bfr, acc[0][nt], 0, 0, 0); \
      acc[1][nt] = __builtin_amdgcn_mfma_f32_16x16x32_bf16(BH[kk * 2 + 1], bfr, acc[1][nt], 0, 0, 0); \
      acc[0][nt] = __builtin_amdgcn_mfma_f32_16x16x32_bf16(BL[kk * 2 + 0], bfr, acc[0][nt], 0, 0, 0); \
      acc[1][nt] = __builtin_amdgcn_mfma_f32_16x16x32_bf16(BL[kk * 2 + 1], bfr, acc[1][nt], 0, 0, 0); }

#define HMATMULX(D, CUR) do { \
    const unsigned short* hsrc = hbuf + (size_t)(CUR) * HB; \
    const unsigned short* lsrc = lbuf + (size_t)(CUR) * HB; \
    v8s c0h[4], c0l[4], c1h[4], c1l[4]; \
    ISSUE(D, c0h, c0l, 0) ISSUE(D, c1h, c1l, 2) \
    WAITV(8); MMC(c0h, c0l, 0) ISSUE(D, c0h, c0l, 4) \
    WAITV(8); MMC(c1h, c1l, 2) ISSUE(D, c1h, c1l, 6) \
    WAITV(8); MMC(c0h, c0l, 4) ISSUE(D, c0h, c0l, 8) \
    WAITV(8); MMC(c1h, c1l, 6) ISSUE(D, c1h, c1l, 10) \
    WAITV(8); MMC(c0h, c0l, 8) ISSUE(D, c0h, c0l, 12) \
    WAITV(8); MMC(c1h, c1l, 10) ISSUE(D, c1h, c1l, 14) \
    WAITV(8); MMC(c0h, c0l, 12) \
    WAITV(0); MMC(c1h, c1l, 14) \
  } while (0)

  // x-part: stage this wave's 32 rows of x_t, then acc = bias + x@Wih^T
#define XINIT(t) do { \
    { int rowl = lane >> 1, half = lane & 1; \
      const float* xp_ = x + (size_t)(bb + p * 32 + rowl) * (Tn * En) + (t) * En + half * 4; \
      *(float4*)&xsp[wid][rowl][half * 4] = *(const float4*)xp_; \
      asm volatile("s_waitcnt lgkmcnt(0)" ::: "memory"); } \
    float4 w0[4], w1[4]; float bv[4]; \
    _Pragma("unroll") for (int nt = 0; nt < 4; nt++) { \
      int col = q64 + nt * 16 + cidx; \
      w0[nt] = *(const float4*)&xwp[col][0]; \
      w1[nt] = *(const float4*)&xwp[col][4]; \
      bv[nt] = biasl[col]; } \
    _Pragma("unroll") for (int mt = 0; mt < 2; mt++) \
      _Pragma("unroll") for (int r = 0; r < 4; r++) { \
        int rowl = mt * 16 + kb * 4 + r; \
        float4 xl = *(const float4*)&xsp[wid][rowl][0]; \
        float4 xh = *(const float4*)&xsp[wid][rowl][4]; \
        _Pragma("unroll") for (int nt = 0; nt < 4; nt++) { \
          float a = bv[nt]; \
          a += xl.x * w0[nt].x + xl.y * w0[nt].y + xl.z * w0[nt].z + xl.w * w0[nt].w; \
          a += xh.x * w1[nt].x + xh.y * w1[nt].y + xh.z * w1[nt].z + xh.w * w1[nt].w; \
          acc[mt][nt][r] = a; } } \
  } while (0)

#define ENC_STEP(D, t) do { \
    const int cur = (t) & 1, nxt = cur ^ 1; \
    v4f acc[2][4]; \
    XINIT(t); \
    POLL((t) + 1); \
    HMATMULX(D, cur); \
    unsigned short* hdst = hbuf + (size_t)nxt * HB; \
    unsigned short* ldst = lbuf + (size_t)nxt * HB; \
    const int j = jj * 32 + q * 16 + cidx; \
    _Pragma("unroll") for (int mt = 0; mt < 2; mt++) \
      _Pragma("unroll") for (int r = 0; r < 4; r++) { \
        float iv = acc[mt][0][r], fv2 = acc[mt][1][r]; \
        float gv = acc[mt][2][r], ov = acc[mt][3][r]; \
        float cn = sigm(fv2) * cst[mt][r] + sigm(iv) * tanh_(gv); \
        float hn = sigm(ov) * tanh_(cn); \
        cst[mt][r] = cn; \
        const int m = bb + p * 32 + mt * 16 + kb * 4 + r; \
        unsigned short hh = f2bf(hn); \
        CAT2(STH_, D)(hdst + (size_t)m * Hn + j, hh); \
        CAT2(STH_, D)(ldst + (size_t)m * Hn + j, f2bf(hn - bf2f(hh))); \
        if ((t) == Tn - 1) { \
          _Pragma("unroll") for (int d = 0; d < 4; d++) { \
            float s = hn * wfcs[d][q * 16 + cidx]; \
            s += __shfl_xor(s, 1, 64); s += __shfl_xor(s, 2, 64); \
            s += __shfl_xor(s, 4, 64); s += __shfl_xor(s, 8, 64); \
            if (cidx == 0) \
              atomicAdd(dpart + ((g * 64 + p * 32 + mt * 16 + kb * 4 + r) * 4 + d), s); } } } \
    asm volatile("s_waitcnt vmcnt(0)" ::: "memory"); \
    if (lane == 0) { \
      unsigned old = atomicAdd(&scnt, 1u); \
      if ((old & 3u) == 3u) STFLAG(myflag, (unsigned)((t) + 2)); } \
  } while (0)

#define DEC_STEP(D, k) do { \
    const int T = Tn + (k); \
    const int cur = (k) & 1, nxt = cur ^ 1; \
    POLL(T + 1); \
    if ((k) == 0) { \
      int row = tid >> 2, d = tid & 3; \
      float pv; \
      asm volatile("global_load_dword %0, %1, off sc0 sc1\n\ts_waitcnt vmcnt(0)" \
                   : "=v"(pv) : "v"(dpart + ((g * 64 + row) * 4 + d)) : "memory"); \
      float xv = x[(size_t)(bb + row) * (Tn * En) + 167 * En + 4 + d]; \
      dl0[row][d] = xv - (pv + bfc[d]); \
      __syncthreads(); \
    } \
    v4f acc[2][4]; \
    _Pragma("unroll") for (int mt = 0; mt < 2; mt++) \
      _Pragma("unroll") for (int r = 0; r < 4; r++) { \
        int rowg = p * 32 + mt * 16 + kb * 4 + r; \
        _Pragma("unroll") for (int nt = 0; nt < 4; nt++) { \
          int col = q64 + nt * 16 + cidx; \
          float a = biasl[col]; \
          if ((k) == 0) { \
            _Pragma("unroll") for (int d2 = 0; d2 < 4; d2++) \
              a += dl0[rowg][d2] * xwdt[d2][col]; } \
          acc[mt][nt][r] = a; } } \
    HMATMULX(D, cur); \
    unsigned short* hdst = hbuf + (size_t)nxt * HB; \
    unsigned short* ldst = lbuf + (size_t)nxt * HB; \
    const int j = jj * 32 + q * 16 + cidx; \
    _Pragma("unroll") for (int mt = 0; mt < 2; mt++) \
      _Pragma("unroll") for (int r = 0; r < 4; r++) { \
        float iv = acc[mt][0][r], fv2 = acc[mt][1][r]; \
        float gv = acc[mt][2][r], ov = acc[mt][3][r]; \
        float cn = sigm(fv2) * cst[mt][r] + sigm(iv) * tanh_(gv); \
        float hn = sigm(ov) * tanh_(cn); \
        cst[mt][r] = cn; \
        const int m = bb + p * 32 + mt * 16 + kb * 4 + r; \
        unsigned short hh = f2bf(hn); \
        CAT2(STH_, D)(hdst + (size_t)m * Hn + j, hh); \
        CAT2(STH_, D)(ldst + (size_t)m * Hn + j, f2bf(hn - bf2f(hh))); \
        float pp = hn * wfcs[3][q * 16 + cidx]; \
        pp += __shfl_xor(pp, 1, 64); pp += __shfl_xor(pp, 2, 64); \
        pp += __shfl_xor(pp, 4, 64); pp += __shfl_xor(pp, 8, 64); \
        if (cidx == 0) { \
          float py = pp + ((jj == 0 && q == 0) ? bfc3s : 0.f); \
          atomicAdd(out + (size_t)m * On + (k), py); } } \
    asm volatile("s_waitcnt vmcnt(0)" ::: "memory"); \
    if (lane == 0) { \
      unsigned old = atomicAdd(&scnt, 1u); \
      if ((old & 3u) == 3u) STFLAG(myflag, (unsigned)(T + 2)); } \
  } while (0)

  // ---- encoder ----
  if (fast) {
    for (int t = 0; t < Tn; t++) ENC_STEP(0, t);
  } else {
    for (int t = 0; t < Tn; t++) ENC_STEP(1, t);
  }

  // ---- transition: reload LDS with folded decoder weights ----
  __syncthreads();
  {
    float4* wq4 = (float4*)wlds;
    for (int i = tid; i < 128 * 64; i += 256) {
      int rl = i >> 6, ch = i & 63;
      int gr = GR_OF(rl);
      wq4[rl * 64 + (ch ^ (rl & 7))] = *(const float4*)(weff_bf + (size_t)gr * Hn + ch * 8);
    }
    for (int i = tid; i < 128; i += 256) {
      int gr = GR_OF(i);
      biasl[i] = beff[gr];
    }
  }
  __syncthreads();

  // ---- decoder ----
  if (fast) {
    for (int k = 0; k < On; k++) DEC_STEP(0, k);
  } else {
    for (int k = 0; k < On; k++) DEC_STEP(1, k);
  }
}

// ---------------- host launch ----------------
extern "C" void kernel_launch(void* const* d_in, const int* in_sizes, int n_in,
                              void* d_out, int out_size, void* d_ws, size_t ws_size,
                              hipStream_t stream) {
  const float* x = (const float*)d_in[0];
  const float* wih_enc = (const float*)d_in[1];
  const float* whh_enc = (const float*)d_in[2];
  const float* b_enc = (const float*)d_in[3];
  const float* wih_dec = (const float*)d_in[4];
  const float* whh_dec = (const float*)d_in[5];
  const float* b_dec = (const float*)d_in[6];
  const float* wfc = (const float*)d_in[7];
  const float* bfc = (const float*)d_in[8];

  char* ws = (char*)d_ws;
  unsigned short* whh_bf = (unsigned short*)ws;                      // 2 MB
  unsigned short* weff_bf = (unsigned short*)(ws + (2u << 20));      // 2 MB
  unsigned short* hbuf = (unsigned short*)(ws + (4u << 20));         // 2 x 1 MB
  unsigned short* lbuf = (unsigned short*)(ws + (6u << 20));         // 2 x 1 MB
  float* beff = (float*)(ws + (8u << 20));                           // 8 KB
  unsigned int* flags = (unsigned int*)(ws + (8u << 20) + 8192);     // 64 KB
  unsigned int* xcds = (unsigned int*)(ws + (8u << 20) + 8192 + 65536);  // 1 KB
  float* dpart = (float*)(ws + (8u << 20) + 8192 + 65536 + 1024);    // 16 KB
  float* out = (float*)d_out;

  setup_weights<<<(G4 * Hn) / 256, 256, 0, stream>>>(whh_enc, whh_dec, wih_dec, wfc,
                                                     whh_bf, weff_bf);
  setup_misc<<<(Bn * On) / 256, 256, 0, stream>>>(b_dec, wih_dec, bfc, beff, out,
                                                  flags, dpart);
  lstm_main<<<256, 256, 0, stream>>>(x, wih_enc, b_enc, wih_dec, wfc, bfc,
                                     whh_bf, weff_bf, beff, hbuf, lbuf, out,
                                     flags, xcds, dpart);
}

// Round 10
// 1410.554 us; speedup vs baseline: 1.4574x; 1.4574x over previous
//
#include <hip/hip_runtime.h>

// Problem sizes
#define Bn 1024
#define Tn 168
#define En 8
#define Hn 512
#define Dn 4
#define On 24
#define G4 2048            // 4*H
#define HB (Bn*Hn)         // elements per h buffer plane

typedef short v8s __attribute__((ext_vector_type(8)));
typedef float v4f __attribute__((ext_vector_type(4)));

#define CAT2(a, b) a##b

__device__ __forceinline__ unsigned short f2bf(float f) {
  union { float f; unsigned u; } v; v.f = f;
  return (unsigned short)((v.u + 0x7fffu + ((v.u >> 16) & 1u)) >> 16);
}
__device__ __forceinline__ float bf2f(unsigned short s) {
  union { unsigned u; float f; } v; v.u = ((unsigned)s) << 16; return v.f;
}
__device__ __forceinline__ float sigm(float x) { return 1.f / (1.f + __expf(-x)); }
__device__ __forceinline__ float tanh_(float x) { return 1.f - 2.f / (__expf(2.f * x) + 1.f); }

// ---- flag ops: ALWAYS device-coherent sc0 sc1 (round-3/6 proven). ----
#define STFLAG(p, v) do { unsigned __vv = (v); \
  asm volatile("global_store_dword %0, %1, off sc0 sc1" :: "v"(p), "v"(__vv) : "memory"); } while (0)
#define LDFLAG(r, p) \
  asm volatile("global_load_dword %0, %1, off sc0 sc1\n\ts_waitcnt vmcnt(0)" \
  : "=v"(r) : "v"(p) : "memory")

// ---- h-plane data ops, path-specialized ----
// D=0 (fast, group co-located on one XCD): plain stores (dirty in shared L2),
//   sc0 loads (L1 bypass, L2 hit). D=1 (slow): device-coherent sc0 sc1.
#define STH_0(p, v) do { unsigned __vv = (v); \
  asm volatile("global_store_short %0, %1, off" :: "v"(p), "v"(__vv) : "memory"); } while (0)
#define STH_1(p, v) do { unsigned __vv = (v); \
  asm volatile("global_store_short %0, %1, off sc0 sc1" :: "v"(p), "v"(__vv) : "memory"); } while (0)
#define LDC_0(dst, p) asm volatile("global_load_dwordx4 %0, %1, off sc0" : "=&v"(dst) : "v"(p))
#define LDC_1(dst, p) asm volatile("global_load_dwordx4 %0, %1, off sc0 sc1" : "=&v"(dst) : "v"(p))

#define WAITV(N) do { \
  asm volatile("s_waitcnt vmcnt(" #N ")" ::: "memory"); \
  __builtin_amdgcn_sched_barrier(0); } while (0)

// ---------------- setup kernels ----------------

__global__ void setup_weights(const float* __restrict__ whh_enc,
                              const float* __restrict__ whh_dec,
                              const float* __restrict__ wih_dec,
                              const float* __restrict__ wfc,
                              unsigned short* __restrict__ whh_bf,
                              unsigned short* __restrict__ weff_bf) {
  int idx = blockIdx.x * 256 + threadIdx.x;
  if (idx >= G4 * Hn) return;
  int r = idx >> 9, c = idx & 511;
  whh_bf[idx] = f2bf(whh_enc[idx]);
  float a = whh_dec[idx];
#pragma unroll
  for (int d = 0; d < 4; d++) a += wih_dec[r * 4 + d] * wfc[d * Hn + c];
  weff_bf[idx] = f2bf(a);
}

__global__ void setup_misc(const float* __restrict__ b_dec,
                           const float* __restrict__ wih_dec,
                           const float* __restrict__ b_fc,
                           float* __restrict__ beff,
                           float* __restrict__ out,
                           unsigned int* __restrict__ flags,
                           float* __restrict__ dpart) {
  int idx = blockIdx.x * 256 + threadIdx.x;
  if (idx < Bn * On) out[idx] = 0.f;
  if (idx < G4) {
    float a = b_dec[idx];
#pragma unroll
    for (int d = 0; d < 4; d++) a += wih_dec[idx * 4 + d] * b_fc[d];
    beff[idx] = a;
  }
  if (idx < 256 * 64) flags[idx] = 0u;   // 256 flags, 256B stride
  if (idx < 16 * 64 * 4) dpart[idx] = 0.f;
}

// ---------------- persistent LSTM kernel ----------------
// 256 blocks x 256 threads, 1 block/CU (VGPR-limited). group g = blockIdx%16
// owns batch rows [64g,64g+64); member jj = blockIdx/16 owns hiddens
// [32jj,32jj+32). K-SPLIT tiling: wave (p,kh), p=wid>>1, kh=wid&1: batch rows
// [32p,32p+32) x ALL 128 gate rows x K-half [256kh,+256). The wave's B half
// (128x256 bf16) lives in 256 VGPRs for the whole run — zero LDS B traffic.
// A-pipeline: depth-2, 1 k-tile per buffer (32 VGPRs) with counted vmcnt —
// kept spill-free by design (round-9 lesson: spills break counted vmcnt).
// K-half partials summed via 32KB LDS exchange + __syncthreads (scnt-gated
// against WAR). Flags: sc0 sc1 always; h-plane fast path when same-XCD.

__global__ void __launch_bounds__(256, 1) lstm_main(
    const float* __restrict__ x,
    const float* __restrict__ wih_enc,
    const float* __restrict__ b_enc,
    const float* __restrict__ wih_dec,
    const float* __restrict__ wfc,
    const float* __restrict__ bfc,
    const unsigned short* __restrict__ whh_bf,
    const unsigned short* __restrict__ weff_bf,
    const float* __restrict__ beff,
    unsigned short* __restrict__ hbuf,   // [2][B*H] hi plane
    unsigned short* __restrict__ lbuf,   // [2][B*H] lo plane
    float* __restrict__ out,
    unsigned int* __restrict__ flags,    // 256 x 64 u32 (256B stride)
    unsigned int* __restrict__ xcds,     // 256 u32: member -> XCC id
    float* __restrict__ dpart) {         // [16][64][4] partial h_enc@Wfc^T
  __shared__ v4f redlds[4][8][64];                // 32KB cross-wave reduce
  __shared__ __align__(16) float xwp[128][12];    // W_ih_enc strip, padded
  __shared__ float xwdt[4][128];                  // W_ih_dec strip, transposed
  __shared__ float biasl[128];
  __shared__ float wfcs[4][32];
  __shared__ __align__(16) float xsp[4][16][12];  // per-wave x strip, padded
  __shared__ float dl0[64][4];
  __shared__ float bfc3s;
  __shared__ unsigned scnt;

  const int tid = threadIdx.x;
  const int wid = tid >> 6;
  const int lane = tid & 63;
  const int cidx = lane & 15;
  const int kb = lane >> 4;
  const int p = wid >> 1;        // batch half
  const int kh = wid & 1;        // K half; also this wave's epilogue tile
  const int g = blockIdx.x & 15;
  const int jj = blockIdx.x >> 4;
  const int bb = g * 64;
  unsigned* myflag = flags + (((g << 4) + jj) << 6);
  const unsigned* fpoll = flags + (((g << 4) + cidx) << 6);

  unsigned xcc;
  asm volatile("s_getreg_b32 %0, hwreg(HW_REG_XCC_ID)" : "=s"(xcc));

#define GR_OF(rl) (((rl) >> 5) * 512 + jj * 32 + ((rl) & 31))

  // ---- phase 0: LDS fills + h zeroing (sc1) + xcds publish ----
  {
    if (tid == 0) scnt = 0u;
    for (int i = tid; i < 128 * 8; i += 256) {
      int c = i & 127, e = i >> 7;
      xwp[c][e] = wih_enc[GR_OF(c) * En + e];
    }
    for (int i = tid; i < 128 * 4; i += 256) {
      int c = i & 127, d = i >> 7;
      xwdt[d][c] = wih_dec[GR_OF(c) * Dn + d];
    }
    for (int i = tid; i < 128; i += 256) biasl[i] = b_enc[GR_OF(i)];
    if (tid < 128) wfcs[tid >> 5][tid & 31] = wfc[(tid >> 5) * Hn + jj * 32 + (tid & 31)];
    if (tid == 0) bfc3s = bfc[3];
    for (int i = tid; i < 64 * 32; i += 256) {
      int m = bb + (i >> 5), j = jj * 32 + (i & 31);
      STH_1(hbuf + (size_t)m * Hn + j, 0);
      STH_1(lbuf + (size_t)m * Hn + j, 0);
    }
    if (tid == 0) {
      unsigned* xp = xcds + ((g << 4) + jj);
      asm volatile("global_store_dword %0, %1, off sc0 sc1" :: "v"(xp), "v"(xcc) : "memory");
    }
  }
  asm volatile("s_waitcnt vmcnt(0)" ::: "memory");
  __syncthreads();
  if (tid == 0) STFLAG(myflag, 1u);   // h_0 + xcds available

#define POLL(TGT) do { \
    int guard = 0; \
    while (true) { \
      unsigned fv = 0xFFFFFFFFu; \
      if (lane < 16) { LDFLAG(fv, fpoll); } \
      if (__ballot(fv < (unsigned)(TGT)) == 0ull) break; \
      __builtin_amdgcn_s_sleep(1); \
      if (++guard > (1 << 21)) break; \
    } } while (0)

  // ---- co-location check ----
  POLL(1);
  unsigned other = xcc;
  if (lane < 16) {
    const unsigned* xq = xcds + ((g << 4) + cidx);
    asm volatile("global_load_dword %0, %1, off sc0 sc1\n\ts_waitcnt vmcnt(0)"
                 : "=v"(other) : "v"(xq) : "memory");
  }
  const int fast = (__ballot(other != xcc) == 0ull) ? 1 : 0;

  // ---- persistent B half in registers: 8nt x 8kt x v8s = 256 VGPR ----
  v8s breg[8][8];
#define LOADB(SRC) do { \
    _Pragma("unroll") for (int nt = 0; nt < 8; nt++) \
      _Pragma("unroll") for (int kt = 0; kt < 8; kt++) \
        breg[nt][kt] = *(const v8s*)((SRC) + (size_t)GR_OF(nt * 16 + cidx) * Hn + \
                                     kh * 256 + kt * 32 + kb * 8); \
  } while (0)
  LOADB(whh_bf);

  float cst[2][4];
#pragma unroll
  for (int a = 0; a < 2; a++)
#pragma unroll
    for (int r = 0; r < 4; r++) cst[a][r] = 0.f;

  const int mbase = bb + p * 32 + kh * 16;          // own epilogue tile rows
  const int mbX = bb + p * 32 + (kh ^ 1) * 16;      // other tile rows
  const size_t abO = (size_t)(mbase + cidx) * Hn + kh * 256 + kb * 8;
  const size_t abX = (size_t)(mbX + cidx) * Hn + kh * 256 + kb * 8;

  // depth-2 A pipeline, 1 k-tile (4 loads, 16 VGPR) per buffer
#define ISSUE1(D, BUF, KT) do { \
    CAT2(LDC_, D)(BUF[0], (const v8s*)(hsrc + abO + (KT) * 32)); \
    CAT2(LDC_, D)(BUF[1], (const v8s*)(lsrc + abO + (KT) * 32)); \
    CAT2(LDC_, D)(BUF[2], (const v8s*)(hsrc + abX + (KT) * 32)); \
    CAT2(LDC_, D)(BUF[3], (const v8s*)(lsrc + abX + (KT) * 32)); } while (0)

#define MMC1(BUF, KT) \
  _Pragma("unroll") for (int nt = 0; nt < 8; nt++) { \
    accO[nt] = __builtin_amdgcn_mfma_f32_16x16x32_bf16(BUF[0], breg[nt][KT], accO[nt], 0, 0, 0); \
    accO[nt] = __builtin_amdgcn_mfma_f32_16x16x32_bf16(BUF[1], breg[nt][KT], accO[nt], 0, 0, 0); \
    accX[nt] = __builtin_amdgcn_mfma_f32_16x16x32_bf16(BUF[2], breg[nt][KT], accX[nt], 0, 0, 0); \
    accX[nt] = __builtin_amdgcn_mfma_f32_16x16x32_bf16(BUF[3], breg[nt][KT], accX[nt], 0, 0, 0); }

#define HMATMUL(D, CUR) do { \
    const unsigned short* hsrc = hbuf + (size_t)(CUR) * HB; \
    const unsigned short* lsrc = lbuf + (size_t)(CUR) * HB; \
    v8s A0[4], A1[4]; \
    ISSUE1(D, A0, 0); ISSUE1(D, A1, 1); \
    WAITV(4); MMC1(A0, 0) ISSUE1(D, A0, 2); \
    WAITV(4); MMC1(A1, 1) ISSUE1(D, A1, 3); \
    WAITV(4); MMC1(A0, 2) ISSUE1(D, A0, 4); \
    WAITV(4); MMC1(A1, 3) ISSUE1(D, A1, 5); \
    WAITV(4); MMC1(A0, 4) ISSUE1(D, A0, 6); \
    WAITV(4); MMC1(A1, 5) ISSUE1(D, A1, 7); \
    WAITV(4); MMC1(A0, 6) \
    WAITV(0); MMC1(A1, 7) \
  } while (0)

  // cross-wave K reduction: write other-tile partial, barrier, add partner's.
  // Safe vs next-step overwrite: a wave cannot pass step t+1's POLL until all
  // 4 waves bumped scnt in step t (i.e. after their redlds reads).
#define REDUCE() do { \
    _Pragma("unroll") for (int nt = 0; nt < 8; nt++) redlds[wid][nt][lane] = accX[nt]; \
    __syncthreads(); \
    _Pragma("unroll") for (int nt = 0; nt < 8; nt++) accO[nt] += redlds[wid ^ 1][nt][lane]; \
  } while (0)

  // stage own 16 rows of x_t; compute bias + x@Wih^T into accO, zero accX
#define XPART(t) do { \
    { int rowl = lane >> 2, qq = lane & 3; \
      const float* xp_ = x + (size_t)(mbase + rowl) * (Tn * En) + (t) * En + qq * 2; \
      float2 xv = *(const float2*)xp_; \
      xsp[wid][rowl][qq * 2] = xv.x; xsp[wid][rowl][qq * 2 + 1] = xv.y; \
      asm volatile("s_waitcnt lgkmcnt(0)" ::: "memory"); } \
    _Pragma("unroll") for (int nt = 0; nt < 8; nt++) { \
      const int rl = nt * 16 + cidx; \
      const float4 w0 = *(const float4*)&xwp[rl][0]; \
      const float4 w1 = *(const float4*)&xwp[rl][4]; \
      const float bv = biasl[rl]; \
      _Pragma("unroll") for (int r = 0; r < 4; r++) { \
        const float4 xl = *(const float4*)&xsp[wid][kb * 4 + r][0]; \
        const float4 xh = *(const float4*)&xsp[wid][kb * 4 + r][4]; \
        accO[nt][r] = bv + xl.x * w0.x + xl.y * w0.y + xl.z * w0.z + xl.w * w0.w \
                         + xh.x * w1.x + xh.y * w1.y + xh.z * w1.z + xh.w * w1.w; \
        accX[nt][r] = 0.f; } } \
  } while (0)

#define ENC_STEP(D, t) do { \
    const int cur = (t) & 1, nxt = cur ^ 1; \
    v4f accO[8], accX[8]; \
    XPART(t); \
    POLL((t) + 1); \
    HMATMUL(D, cur); \
    REDUCE(); \
    unsigned short* hdst = hbuf + (size_t)nxt * HB; \
    unsigned short* ldst = lbuf + (size_t)nxt * HB; \
    _Pragma("unroll") for (int r = 0; r < 4; r++) { \
      float hv[2]; \
      _Pragma("unroll") for (int th = 0; th < 2; th++) { \
        float iv = accO[th][r], fv2 = accO[2 + th][r]; \
        float gv = accO[4 + th][r], ov = accO[6 + th][r]; \
        float cn = sigm(fv2) * cst[th][r] + sigm(iv) * tanh_(gv); \
        float hn = sigm(ov) * tanh_(cn); \
        cst[th][r] = cn; hv[th] = hn; \
        const int m = mbase + kb * 4 + r; \
        const int j = jj * 32 + th * 16 + cidx; \
        unsigned short hh = f2bf(hn); \
        CAT2(STH_, D)(hdst + (size_t)m * Hn + j, hh); \
        CAT2(STH_, D)(ldst + (size_t)m * Hn + j, f2bf(hn - bf2f(hh))); } \
      if ((t) == Tn - 1) { \
        _Pragma("unroll") for (int d = 0; d < 4; d++) { \
          float s = hv[0] * wfcs[d][cidx] + hv[1] * wfcs[d][16 + cidx]; \
          s += __shfl_xor(s, 1, 64); s += __shfl_xor(s, 2, 64); \
          s += __shfl_xor(s, 4, 64); s += __shfl_xor(s, 8, 64); \
          if (cidx == 0) \
            atomicAdd(dpart + ((size_t)(mbase - bb + g * 64 + kb * 4 + r) * 4 + d), s); } } } \
    asm volatile("s_waitcnt vmcnt(0)" ::: "memory"); \
    if (lane == 0) { \
      unsigned oldv = atomicAdd(&scnt, 1u); \
      if ((oldv & 3u) == 3u) STFLAG(myflag, (unsigned)((t) + 2)); } \
  } while (0)

#define DEC_STEP(D, k) do { \
    const int T = Tn + (k); \
    const int cur = (k) & 1, nxt = cur ^ 1; \
    POLL(T + 1); \
    if ((k) == 0) { \
      int row = tid >> 2, d = tid & 3; \
      float pv; \
      asm volatile("global_load_dword %0, %1, off sc0 sc1\n\ts_waitcnt vmcnt(0)" \
                   : "=v"(pv) : "v"(dpart + ((g * 64 + row) * 4 + d)) : "memory"); \
      float xv = x[(size_t)(bb + row) * (Tn * En) + 167 * En + 4 + d]; \
      dl0[row][d] = xv - (pv + bfc[d]); \
      __syncthreads(); \
    } \
    v4f accO[8], accX[8]; \
    _Pragma("unroll") for (int nt = 0; nt < 8; nt++) { \
      const int rl = nt * 16 + cidx; \
      const float bv = biasl[rl]; \
      _Pragma("unroll") for (int r = 0; r < 4; r++) { \
        float a = bv; \
        if ((k) == 0) { \
          const int rloc = mbase - bb + kb * 4 + r; \
          _Pragma("unroll") for (int d2 = 0; d2 < 4; d2++) \
            a += dl0[rloc][d2] * xwdt[d2][rl]; } \
        accO[nt][r] = a; accX[nt][r] = 0.f; } } \
    HMATMUL(D, cur); \
    REDUCE(); \
    unsigned short* hdst = hbuf + (size_t)nxt * HB; \
    unsigned short* ldst = lbuf + (size_t)nxt * HB; \
    _Pragma("unroll") for (int r = 0; r < 4; r++) { \
      float hv[2]; \
      _Pragma("unroll") for (int th = 0; th < 2; th++) { \
        float iv = accO[th][r], fv2 = accO[2 + th][r]; \
        float gv = accO[4 + th][r], ov = accO[6 + th][r]; \
        float cn = sigm(fv2) * cst[th][r] + sigm(iv) * tanh_(gv); \
        float hn = sigm(ov) * tanh_(cn); \
        cst[th][r] = cn; hv[th] = hn; \
        const int m = mbase + kb * 4 + r; \
        const int j = jj * 32 + th * 16 + cidx; \
        unsigned short hh = f2bf(hn); \
        CAT2(STH_, D)(hdst + (size_t)m * Hn + j, hh); \
        CAT2(STH_, D)(ldst + (size_t)m * Hn + j, f2bf(hn - bf2f(hh))); } \
      float pp = hv[0] * wfcs[3][cidx] + hv[1] * wfcs[3][16 + cidx]; \
      pp += __shfl_xor(pp, 1, 64); pp += __shfl_xor(pp, 2, 64); \
      pp += __shfl_xor(pp, 4, 64); pp += __shfl_xor(pp, 8, 64); \
      if (cidx == 0) { \
        const int m = mbase + kb * 4 + r; \
        float py = pp + (jj == 0 ? bfc3s : 0.f); \
        atomicAdd(out + (size_t)m * On + (k), py); } } \
    asm volatile("s_waitcnt vmcnt(0)" ::: "memory"); \
    if (lane == 0) { \
      unsigned oldv = atomicAdd(&scnt, 1u); \
      if ((oldv & 3u) == 3u) STFLAG(myflag, (unsigned)(T + 2)); } \
  } while (0)

  // ---- encoder ----
  if (fast) {
    for (int t = 0; t < Tn; t++) ENC_STEP(0, t);
  } else {
    for (int t = 0; t < Tn; t++) ENC_STEP(1, t);
  }

  // ---- transition: reload B regs + bias with folded decoder weights ----
  __syncthreads();
  LOADB(weff_bf);
  for (int i = tid; i < 128; i += 256) biasl[i] = beff[GR_OF(i)];
  __syncthreads();

  // ---- decoder ----
  if (fast) {
    for (int k = 0; k < On; k++) DEC_STEP(0, k);
  } else {
    for (int k = 0; k < On; k++) DEC_STEP(1, k);
  }
}

// ---------------- host launch ----------------
extern "C" void kernel_launch(void* const* d_in, const int* in_sizes, int n_in,
                              void* d_out, int out_size, void* d_ws, size_t ws_size,
                              hipStream_t stream) {
  const float* x = (const float*)d_in[0];
  const float* wih_enc = (const float*)d_in[1];
  const float* whh_enc = (const float*)d_in[2];
  const float* b_enc = (const float*)d_in[3];
  const float* wih_dec = (const float*)d_in[4];
  const float* whh_dec = (const float*)d_in[5];
  const float* b_dec = (const float*)d_in[6];
  const float* wfc = (const float*)d_in[7];
  const float* bfc = (const float*)d_in[8];

  char* ws = (char*)d_ws;
  unsigned short* whh_bf = (unsigned short*)ws;                      // 2 MB
  unsigned short* weff_bf = (unsigned short*)(ws + (2u << 20));      // 2 MB
  unsigned short* hbuf = (unsigned short*)(ws + (4u << 20));         // 2 x 1 MB
  unsigned short* lbuf = (unsigned short*)(ws + (6u << 20));         // 2 x 1 MB
  float* beff = (float*)(ws + (8u << 20));                           // 8 KB
  unsigned int* flags = (unsigned int*)(ws + (8u << 20) + 8192);     // 64 KB
  unsigned int* xcds = (unsigned int*)(ws + (8u << 20) + 8192 + 65536);  // 1 KB
  float* dpart = (float*)(ws + (8u << 20) + 8192 + 65536 + 1024);    // 16 KB
  float* out = (float*)d_out;

  setup_weights<<<(G4 * Hn) / 256, 256, 0, stream>>>(whh_enc, whh_dec, wih_dec, wfc,
                                                     whh_bf, weff_bf);
  setup_misc<<<(Bn * On) / 256, 256, 0, stream>>>(b_dec, wih_dec, bfc, beff, out,
                                                  flags, dpart);
  lstm_main<<<256, 256, 0, stream>>>(x, wih_enc, b_enc, wih_dec, wfc, bfc,
                                     whh_bf, weff_bf, beff, hbuf, lbuf, out,
                                     flags, xcds, dpart);
}